// Round 7
// baseline (440.408 us; speedup 1.0000x reference)
//
#include <hip/hip_runtime.h>
#include <hip/hip_cooperative_groups.h>

namespace cg = cooperative_groups;

#define N_   64
#define C_   2048
#define P_   5
#define CM_  3328   // C_ + P_*256
#define LOC_ 1280   // P_*256
#define SEGC 8      // K segments for loc GEMM  (2048/256)
#define SEGM 13     // K segments for merge GEMM (3328/256)

#define PITCH  28   // phase-B LDS row pitch (floats)
#define WPITCH 72   // GEMM LDS tile pitch (bf16)

typedef __attribute__((ext_vector_type(8))) short bf16x8;
typedef __attribute__((ext_vector_type(4))) float f32x4;

__device__ __forceinline__ unsigned short f2bf(float f) {   // fp32 -> bf16 RNE
  unsigned u = __float_as_uint(f);
  u = (u + 0x7FFFu + ((u >> 16) & 1u)) >> 16;
  return (unsigned short)u;
}
__device__ __forceinline__ unsigned pack2(float lo, float hi) {
  return (unsigned)f2bf(lo) | ((unsigned)f2bf(hi) << 16);
}

// MFMA 64x64 tile over one 256-wide K segment (A bf16 staged as-is, W fp32
// converted to bf16 during staging). Whole block participates.
__device__ __forceinline__ void mfma_seg(const uint4* __restrict__ aRow,
                                         const float4* __restrict__ wRow,
                                         unsigned short* As, unsigned short* Ws,
                                         f32x4 acc[4]) {
  const int t  = threadIdx.x;
  const int kq = t & 3;
  const int row = t >> 2;
  const int w  = t >> 6;
  const int l  = t & 63;
  unsigned short* aw = &As[row * WPITCH + kq * 16];
  unsigned short* ww = &Ws[row * WPITCH + kq * 16];
  const int arow16 = (16 * w + (l & 15)) * WPITCH + (l >> 4) * 8;
  const int brow16 = (l & 15) * WPITCH + (l >> 4) * 8;
  for (int g = 0; g < 4; ++g) {
    uint4 a0 = aRow[g * 8 + 0], a1 = aRow[g * 8 + 1];
    float4 w0 = wRow[g * 16 + 0], w1 = wRow[g * 16 + 1],
           w2 = wRow[g * 16 + 2], w3 = wRow[g * 16 + 3];
    uint4 pw0, pw1;
    pw0.x = pack2(w0.x, w0.y); pw0.y = pack2(w0.z, w0.w);
    pw0.z = pack2(w1.x, w1.y); pw0.w = pack2(w1.z, w1.w);
    pw1.x = pack2(w2.x, w2.y); pw1.y = pack2(w2.z, w2.w);
    pw1.z = pack2(w3.x, w3.y); pw1.w = pack2(w3.z, w3.w);
    __syncthreads();                              // prev users of As/Ws done
    *(uint4*)aw = a0; *(uint4*)(aw + 8) = a1;
    *(uint4*)ww = pw0; *(uint4*)(ww + 8) = pw1;
    __syncthreads();
#pragma unroll
    for (int s = 0; s < 2; ++s) {
      bf16x8 af = *(const bf16x8*)&As[arow16 + s * 32];
#pragma unroll
      for (int jm = 0; jm < 4; ++jm) {
        bf16x8 bf = *(const bf16x8*)&Ws[jm * 16 * WPITCH + brow16 + s * 32];
        acc[jm] = __builtin_amdgcn_mfma_f32_16x16x32_bf16(af, bf, acc[jm], 0, 0, 0);
      }
    }
  }
}

__global__ __launch_bounds__(256) void mega(
    const float* __restrict__ x, const float* __restrict__ poses,
    const float* __restrict__ local_w,
    const float* __restrict__ lb, const float* __restrict__ lg,
    const float* __restrict__ lbe, const float* __restrict__ lm,
    const float* __restrict__ lv,
    const float* __restrict__ merge_w,
    const float* __restrict__ mb, const float* __restrict__ mg,
    const float* __restrict__ mbe, const float* __restrict__ mm,
    const float* __restrict__ mv,
    unsigned short* __restrict__ avgB, unsigned short* __restrict__ catB,
    float* __restrict__ locP, float* __restrict__ mrgP,
    float* __restrict__ out) {
  __shared__ __align__(16) char smem[2 * 256 * PITCH * 4];   // 57344 B, reused per phase
  cg::grid_group grid = cg::this_grid();
  const int b = blockIdx.x;
  const int t = threadIdx.x;

  // ================= Phase B: pooled box-avgs + global max =================
  {
    float* ldsB = (float*)smem;                  // 2 buffers of 256*PITCH floats
    const float4* x4 = (const float4*)x;
    for (int unit = b; unit < 512; unit += 256) {
      const int n  = unit >> 3;
      const int cb = (unit & 7) << 8;
      const int chbase = n * C_ + cb;

      unsigned MH[P_], MW[P_];
      float INV[P_];
      const float* kpn = poses + (size_t)n * 68;
#pragma unroll
      for (int p = 0; p < P_; ++p) {
        const float* kp = kpn + 16 * p;
        float px = kp[0], py = kp[1], z = kp[2];
        float bx = fminf(fmaxf(px - 0.25f, 0.f), 0.75f) * z;
        float by = fminf(fmaxf(py - 0.25f, 0.f), 0.75f) * z;
        float bw = 0.5f * z;
        float bh = 0.5f * z;
        int xs = (int)fmaxf(0.f,  rintf(12.f * bx));
        int xe = (int)fminf(11.f, rintf(12.f * (bx + bw)));
        int ys = (int)fmaxf(0.f,  rintf(24.f * by));
        int ye = (int)fminf(23.f, rintf(24.f * (by + bh)));
        MH[p] = ((1u << ye) - 1u) & ~((1u << ys) - 1u);
        MW[p] = ((1u << xe) - 1u) & ~((1u << xs) - 1u);
        int area = (ye - ys) * (xe - xs);
        INV[p] = area > 0 ? 1.f / (float)area : 1.f;
      }

      size_t gbase[6];
      int    loff[6];
#pragma unroll
      for (int k = 0; k < 6; ++k) {
        unsigned flat = k * 256 + t;             // 0..1535
        unsigned cl = flat / 6u;
        unsigned j  = flat - 6u * cl;
        gbase[k] = (size_t)(chbase + cl) * 72 + j;
        loff[k]  = cl * PITCH + 4 * j;
      }

      float4 rg[6];
      auto loadRegs = [&](int ci) {
#pragma unroll
        for (int k = 0; k < 6; ++k) rg[k] = x4[gbase[k] + ci * 6];
      };
      auto writeRegs = [&](int db) {
#pragma unroll
        for (int k = 0; k < 6; ++k) *(float4*)&ldsB[db * 256 * PITCH + loff[k]] = rg[k];
      };

      float s[P_] = {0.f, 0.f, 0.f, 0.f, 0.f};
      float mx = -3.402823466e+38f;

      __syncthreads();                           // LDS safe to reuse
      loadRegs(0);
      writeRegs(0);
      __syncthreads();
      for (int ci = 0; ci < 12; ++ci) {
        if (ci + 1 < 12) loadRegs(ci + 1);
        const float* row = &ldsB[(ci & 1) * 256 * PITCH + t * PITCH];
#pragma unroll
        for (int r = 0; r < 2; ++r) {
          int h = 2 * ci + r;
          float4 a = *(const float4*)(row + r * 12 + 0);
          float4 bq = *(const float4*)(row + r * 12 + 4);
          float4 c = *(const float4*)(row + r * 12 + 8);
          float m1 = fmaxf(fmaxf(a.x, a.y), fmaxf(a.z, a.w));
          float m2 = fmaxf(fmaxf(bq.x, bq.y), fmaxf(bq.z, bq.w));
          float m3 = fmaxf(fmaxf(c.x, c.y), fmaxf(c.z, c.w));
          mx = fmaxf(mx, fmaxf(m1, fmaxf(m2, m3)));
#pragma unroll
          for (int p = 0; p < P_; ++p) {
            unsigned cm = ((MH[p] >> h) & 1u) ? MW[p] : 0u;   // wave-uniform
            if (cm) {
              float t0 = ((cm & 0x001u) ? a.x : 0.f) + ((cm & 0x002u) ? a.y : 0.f);
              float t1 = ((cm & 0x004u) ? a.z : 0.f) + ((cm & 0x008u) ? a.w : 0.f);
              float t2 = ((cm & 0x010u) ? bq.x : 0.f) + ((cm & 0x020u) ? bq.y : 0.f);
              float t3 = ((cm & 0x040u) ? bq.z : 0.f) + ((cm & 0x080u) ? bq.w : 0.f);
              float t4 = ((cm & 0x100u) ? c.x : 0.f) + ((cm & 0x200u) ? c.y : 0.f);
              float t5 = ((cm & 0x400u) ? c.z : 0.f) + ((cm & 0x800u) ? c.w : 0.f);
              s[p] += ((t0 + t1) + (t2 + t3)) + (t4 + t5);
            }
          }
        }
        if (ci + 1 < 12) {
          writeRegs((ci + 1) & 1);               // vmcnt wait lands after compute
          __syncthreads();
        }
      }

      int c = cb + t;
      catB[(size_t)n * CM_ + LOC_ + c] = f2bf(mx);
#pragma unroll
      for (int p = 0; p < P_; ++p)
        avgB[((size_t)n * 5 + p) * C_ + c] = f2bf(s[p] * INV[p]);
    }
  }
  grid.sync();

  // ================= Phase C: loc GEMM partials =================
  if (b < 160) {                                 // 5p * 4kt * 8sg
    unsigned short* As = (unsigned short*)smem;
    unsigned short* Ws = As + 64 * WPITCH;
    int p  = b >> 5;
    int kt = (b >> 3) & 3;
    int sg = b & 7;
    const int row = t >> 2, kq = t & 3, w = t >> 6, l = t & 63;
    const uint4*  aRow = (const uint4*)avgB + ((size_t)row * 5 + p) * 256 + sg * 32 + kq * 2;
    const float4* wRow = (const float4*)(local_w + ((size_t)p * 256 + kt * 64 + row) * C_
                                         + sg * 256 + kq * 16);
    f32x4 acc[4] = {{0,0,0,0},{0,0,0,0},{0,0,0,0},{0,0,0,0}};
    mfma_seg(aRow, wRow, As, Ws, acc);
    float* outp = locP + (size_t)sg * (N_ * LOC_);
#pragma unroll
    for (int jm = 0; jm < 4; ++jm)
#pragma unroll
      for (int r = 0; r < 4; ++r)
        outp[(size_t)(16 * w + (l >> 4) * 4 + r) * LOC_ + p * 256 + kt * 64 + jm * 16 + (l & 15)]
          = acc[jm][r];
  }
  grid.sync();

  // ================= Phase C2: reduce + BN + ReLU -> catB loc region =================
  for (int i = b * 256 + t; i < N_ * LOC_; i += 256 * 256) {
    int n = i / LOC_;
    int q = i - n * LOC_;
    float s = 0.f;
#pragma unroll
    for (int sg = 0; sg < SEGC; ++sg) s += locP[(size_t)sg * (N_ * LOC_) + i];
    float sc = lg[q] / sqrtf(lv[q] + 1e-5f);
    float v = (s + lb[q] - lm[q]) * sc + lbe[q];
    catB[(size_t)n * CM_ + q] = f2bf(fmaxf(v, 0.f));
  }
  grid.sync();

  // ================= Phase D: merge GEMM partials =================
  {
    unsigned short* As = (unsigned short*)smem;
    unsigned short* Ws = As + 64 * WPITCH;
    for (int u = b; u < 32 * SEGM; u += 256) {   // 416 tiles
      int jt = u / SEGM;
      int sg = u - jt * SEGM;
      const int row = t >> 2, kq = t & 3, w = t >> 6, l = t & 63;
      const uint4*  aRow = (const uint4*)catB + (size_t)row * 416 + sg * 32 + kq * 2;
      const float4* wRow = (const float4*)(merge_w + (size_t)(jt * 64 + row) * CM_
                                           + sg * 256 + kq * 16);
      f32x4 acc[4] = {{0,0,0,0},{0,0,0,0},{0,0,0,0},{0,0,0,0}};
      mfma_seg(aRow, wRow, As, Ws, acc);         // leading sync inside
      float* outp = mrgP + (size_t)sg * (N_ * C_);
#pragma unroll
      for (int jm = 0; jm < 4; ++jm)
#pragma unroll
        for (int r = 0; r < 4; ++r)
          outp[(size_t)(16 * w + (l >> 4) * 4 + r) * C_ + jt * 64 + jm * 16 + (l & 15)]
            = acc[jm][r];
    }
  }
  grid.sync();

  // ================= Phase E: reduce + BN + ReLU + L2 normalize =================
  if (b < N_) {
    int n = b;
    float* red = (float*)smem;
    float z[8]; float ss = 0.f;
#pragma unroll
    for (int r = 0; r < 8; ++r) {
      int j = t + (r << 8);
      float y = 0.f;
#pragma unroll
      for (int sg = 0; sg < SEGM; ++sg) y += mrgP[(size_t)sg * (N_ * C_) + (size_t)n * C_ + j];
      float sc = mg[j] / sqrtf(mv[j] + 1e-5f);
      float v = (y + mb[j] - mm[j]) * sc + mbe[j];
      v = fmaxf(v, 0.f);
      z[r] = v; ss += v * v;
    }
#pragma unroll
    for (int off = 32; off; off >>= 1) ss += __shfl_xor(ss, off, 64);
    __syncthreads();                             // smem reuse safe
    if ((t & 63) == 0) red[t >> 6] = ss;
    __syncthreads();
    float tot = red[0] + red[1] + red[2] + red[3];
    float inv = 1.f / fmaxf(sqrtf(tot), 1e-12f);
#pragma unroll
    for (int r = 0; r < 8; ++r) out[(size_t)n * C_ + t + (r << 8)] = z[r] * inv;
  }
}

extern "C" void kernel_launch(void* const* d_in, const int* in_sizes, int n_in,
                              void* d_out, int out_size, void* d_ws, size_t ws_size,
                              hipStream_t stream) {
  const float* x          = (const float*)d_in[0];
  const float* poses      = (const float*)d_in[1];
  const float* local_w    = (const float*)d_in[2];
  const float* local_b    = (const float*)d_in[3];
  const float* local_g    = (const float*)d_in[4];
  const float* local_be   = (const float*)d_in[5];
  const float* local_m    = (const float*)d_in[6];
  const float* local_v    = (const float*)d_in[7];
  const float* merge_w    = (const float*)d_in[8];
  const float* merge_b    = (const float*)d_in[9];
  const float* merge_g    = (const float*)d_in[10];
  const float* merge_be   = (const float*)d_in[11];
  const float* merge_m    = (const float*)d_in[12];
  const float* merge_v    = (const float*)d_in[13];

  char* ws = (char*)d_ws;
  unsigned short* catB = (unsigned short*)ws;                 // 64*3328 bf16
  unsigned short* avgB = (unsigned short*)(ws + 425984);      // 64*5*2048 bf16
  float* locP = (float*)(ws + 1736704);                       // 8*64*1280 f32
  float* mrgP = (float*)(ws + 4358144);                       // 13*64*2048 f32
  float* out  = (float*)d_out;

  void* args[] = {
    (void*)&x, (void*)&poses, (void*)&local_w,
    (void*)&local_b, (void*)&local_g, (void*)&local_be, (void*)&local_m, (void*)&local_v,
    (void*)&merge_w, (void*)&merge_b, (void*)&merge_g, (void*)&merge_be,
    (void*)&merge_m, (void*)&merge_v,
    (void*)&avgB, (void*)&catB, (void*)&locP, (void*)&mrgP, (void*)&out,
  };
  hipLaunchCooperativeKernel((const void*)mega, dim3(256), dim3(256), args, 0, stream);
}

// Round 8
// 297.944 us; speedup vs baseline: 1.4782x; 1.4782x over previous
//
#include <hip/hip_runtime.h>

#define N_   64
#define C_   2048
#define P_   5
#define CM_  3328   // C_ + P_*256
#define LOC_ 1280   // P_*256
#define SEGC 16     // K segments for loc GEMM  (2048/128)
#define SEGM 26     // K segments for merge GEMM (3328/128)

#define PITCH  28   // kB LDS row pitch (floats)
#define WPITCH 72   // GEMM LDS tile pitch (bf16)

typedef __attribute__((ext_vector_type(8))) short bf16x8;
typedef __attribute__((ext_vector_type(4))) float f32x4;

__device__ __forceinline__ unsigned short f2bf(float f) {   // fp32 -> bf16 RNE
  unsigned u = __float_as_uint(f);
  u = (u + 0x7FFFu + ((u >> 16) & 1u)) >> 16;
  return (unsigned short)u;
}
__device__ __forceinline__ unsigned pack2(float lo, float hi) {
  return (unsigned)f2bf(lo) | ((unsigned)f2bf(hi) << 16);
}

// ---------- Kernel B: one THREAD per channel; x staged via double-buffered LDS ----------
__global__ __launch_bounds__(256) void kB(const float* __restrict__ x,
    const float* __restrict__ poses,
    unsigned short* __restrict__ avgB, unsigned short* __restrict__ catB) {
  __shared__ float lds[2][256 * PITCH];
  const int t  = threadIdx.x;
  const int n  = blockIdx.x >> 3;
  const int cb = (blockIdx.x & 7) << 8;
  const int chbase = n * C_ + cb;

  unsigned MH[P_], MW[P_];
  float INV[P_];
  const float* kpn = poses + (size_t)n * 68;
#pragma unroll
  for (int p = 0; p < P_; ++p) {
    const float* kp = kpn + 16 * p;
    float px = kp[0], py = kp[1], z = kp[2];
    float bx = fminf(fmaxf(px - 0.25f, 0.f), 0.75f) * z;
    float by = fminf(fmaxf(py - 0.25f, 0.f), 0.75f) * z;
    float bw = 0.5f * z;
    float bh = 0.5f * z;
    int xs = (int)fmaxf(0.f,  rintf(12.f * bx));
    int xe = (int)fminf(11.f, rintf(12.f * (bx + bw)));
    int ys = (int)fmaxf(0.f,  rintf(24.f * by));
    int ye = (int)fminf(23.f, rintf(24.f * (by + bh)));
    MH[p] = ((1u << ye) - 1u) & ~((1u << ys) - 1u);
    MW[p] = ((1u << xe) - 1u) & ~((1u << xs) - 1u);
    int area = (ye - ys) * (xe - xs);
    INV[p] = area > 0 ? 1.f / (float)area : 1.f;
  }

  const float4* x4 = (const float4*)x;
  size_t gbase[6];
  int    loff[6];
#pragma unroll
  for (int k = 0; k < 6; ++k) {
    unsigned flat = k * 256 + t;
    unsigned cl = flat / 6u;
    unsigned j  = flat - 6u * cl;
    gbase[k] = (size_t)(chbase + cl) * 72 + j;
    loff[k]  = cl * PITCH + 4 * j;
  }

  float4 rg[6];
  auto loadRegs = [&](int ci) {
#pragma unroll
    for (int k = 0; k < 6; ++k) rg[k] = x4[gbase[k] + ci * 6];
  };
  auto writeRegs = [&](int db) {
#pragma unroll
    for (int k = 0; k < 6; ++k) *(float4*)&lds[db][loff[k]] = rg[k];
  };

  float s[P_] = {0.f, 0.f, 0.f, 0.f, 0.f};
  float mx = -3.402823466e+38f;

  loadRegs(0);
  writeRegs(0);
  __syncthreads();
  for (int ci = 0; ci < 12; ++ci) {
    if (ci + 1 < 12) loadRegs(ci + 1);
    const float* row = &lds[ci & 1][t * PITCH];
#pragma unroll
    for (int r = 0; r < 2; ++r) {
      int h = 2 * ci + r;
      float4 a = *(const float4*)(row + r * 12 + 0);
      float4 b = *(const float4*)(row + r * 12 + 4);
      float4 c = *(const float4*)(row + r * 12 + 8);
      float m1 = fmaxf(fmaxf(a.x, a.y), fmaxf(a.z, a.w));
      float m2 = fmaxf(fmaxf(b.x, b.y), fmaxf(b.z, b.w));
      float m3 = fmaxf(fmaxf(c.x, c.y), fmaxf(c.z, c.w));
      mx = fmaxf(mx, fmaxf(m1, fmaxf(m2, m3)));
#pragma unroll
      for (int p = 0; p < P_; ++p) {
        unsigned cm = ((MH[p] >> h) & 1u) ? MW[p] : 0u;   // wave-uniform
        if (cm) {
          float t0 = ((cm & 0x001u) ? a.x : 0.f) + ((cm & 0x002u) ? a.y : 0.f);
          float t1 = ((cm & 0x004u) ? a.z : 0.f) + ((cm & 0x008u) ? a.w : 0.f);
          float t2 = ((cm & 0x010u) ? b.x : 0.f) + ((cm & 0x020u) ? b.y : 0.f);
          float t3 = ((cm & 0x040u) ? b.z : 0.f) + ((cm & 0x080u) ? b.w : 0.f);
          float t4 = ((cm & 0x100u) ? c.x : 0.f) + ((cm & 0x200u) ? c.y : 0.f);
          float t5 = ((cm & 0x400u) ? c.z : 0.f) + ((cm & 0x800u) ? c.w : 0.f);
          s[p] += ((t0 + t1) + (t2 + t3)) + (t4 + t5);
        }
      }
    }
    if (ci + 1 < 12) {
      writeRegs((ci + 1) & 1);                   // vmcnt wait lands after compute
      __syncthreads();
    }
  }

  int c = cb + t;
  catB[(size_t)n * CM_ + LOC_ + c] = f2bf(mx);
#pragma unroll
  for (int p = 0; p < P_; ++p)
    avgB[((size_t)n * 5 + p) * C_ + c] = f2bf(s[p] * INV[p]);
}

// ---------- MFMA 64x64 tile over one K segment of GSEG*64; pipelined staging.
// Loads for chunk g+1 are issued before chunk g's MFMAs so the vmcnt wait
// (at the next LDS write) lands after a full MFMA block. ----------
template<int GSEG>
__device__ __forceinline__ void mfma_seg(const uint4* __restrict__ aRow,
                                         const float4* __restrict__ wRow,
                                         unsigned short* As, unsigned short* Ws,
                                         f32x4 acc[4]) {
  const int t  = threadIdx.x;
  const int kq = t & 3;
  const int row = t >> 2;
  const int w  = t >> 6;
  const int l  = t & 63;
  unsigned short* aw = &As[row * WPITCH + kq * 16];
  unsigned short* ww = &Ws[row * WPITCH + kq * 16];
  const int arow16 = (16 * w + (l & 15)) * WPITCH + (l >> 4) * 8;
  const int brow16 = (l & 15) * WPITCH + (l >> 4) * 8;
  uint4 a0 = aRow[0], a1 = aRow[1];
  float4 w0 = wRow[0], w1 = wRow[1], w2 = wRow[2], w3 = wRow[3];
  for (int g = 0; g < GSEG; ++g) {
    uint4 pw0, pw1;
    pw0.x = pack2(w0.x, w0.y); pw0.y = pack2(w0.z, w0.w);
    pw0.z = pack2(w1.x, w1.y); pw0.w = pack2(w1.z, w1.w);
    pw1.x = pack2(w2.x, w2.y); pw1.y = pack2(w2.z, w2.w);
    pw1.z = pack2(w3.x, w3.y); pw1.w = pack2(w3.z, w3.w);
    __syncthreads();                              // prev users of As/Ws done
    *(uint4*)aw = a0; *(uint4*)(aw + 8) = a1;
    *(uint4*)ww = pw0; *(uint4*)(ww + 8) = pw1;
    __syncthreads();
    if (g + 1 < GSEG) {                           // issue next chunk's loads now
      a0 = aRow[(g + 1) * 8 + 0]; a1 = aRow[(g + 1) * 8 + 1];
      w0 = wRow[(g + 1) * 16 + 0]; w1 = wRow[(g + 1) * 16 + 1];
      w2 = wRow[(g + 1) * 16 + 2]; w3 = wRow[(g + 1) * 16 + 3];
    }
#pragma unroll
    for (int s = 0; s < 2; ++s) {
      bf16x8 af = *(const bf16x8*)&As[arow16 + s * 32];
#pragma unroll
      for (int jm = 0; jm < 4; ++jm) {
        bf16x8 bf = *(const bf16x8*)&Ws[jm * 16 * WPITCH + brow16 + s * 32];
        acc[jm] = __builtin_amdgcn_mfma_f32_16x16x32_bf16(af, bf, acc[jm], 0, 0, 0);
      }
    }
  }
}

// loc GEMM partials: avgB(bf16) x local_w[p]^T -> locP[seg][64][1280] (f32)
__global__ __launch_bounds__(256) void kC(const unsigned short* __restrict__ avgB,
                                          const float* __restrict__ local_w,
                                          float* __restrict__ locP) {
  __shared__ unsigned short As[64 * WPITCH];
  __shared__ unsigned short Ws[64 * WPITCH];
  int b  = blockIdx.x;            // 320 = 5p * 4kt * 16sg
  int p  = b >> 6;
  int kt = (b >> 4) & 3;
  int sg = b & 15;                // 128-wide K segment
  const int t = threadIdx.x, row = t >> 2, kq = t & 3, w = t >> 6, l = t & 63;
  const uint4*  aRow = (const uint4*)avgB + ((size_t)row * 5 + p) * 256 + sg * 16 + kq * 2;
  const float4* wRow = (const float4*)(local_w + ((size_t)p * 256 + kt * 64 + row) * C_
                                       + sg * 128 + kq * 16);
  f32x4 acc[4] = {{0,0,0,0},{0,0,0,0},{0,0,0,0},{0,0,0,0}};
  mfma_seg<2>(aRow, wRow, As, Ws, acc);
  float* outp = locP + (size_t)sg * (N_ * LOC_);
#pragma unroll
  for (int jm = 0; jm < 4; ++jm)
#pragma unroll
    for (int r = 0; r < 4; ++r)
      outp[(size_t)(16 * w + (l >> 4) * 4 + r) * LOC_ + p * 256 + kt * 64 + jm * 16 + (l & 15)]
        = acc[jm][r];
}

// reduce locP over segs + BN + ReLU -> catB[:, 0:1280] (bf16)
__global__ __launch_bounds__(256) void kC2(const float* __restrict__ locP,
    const float* __restrict__ lb, const float* __restrict__ lg, const float* __restrict__ lbe,
    const float* __restrict__ lm, const float* __restrict__ lv,
    unsigned short* __restrict__ catB) {
  int i = blockIdx.x * 256 + threadIdx.x;   // < 64*1280
  int n = i / LOC_;
  int q = i - n * LOC_;
  float s = 0.f;
#pragma unroll
  for (int sg = 0; sg < SEGC; ++sg) s += locP[(size_t)sg * (N_ * LOC_) + i];
  float sc = lg[q] / sqrtf(lv[q] + 1e-5f);
  float v = (s + lb[q] - lm[q]) * sc + lbe[q];
  catB[(size_t)n * CM_ + q] = f2bf(fmaxf(v, 0.f));
}

// merge GEMM partials: catB(bf16) x merge_w^T -> mrgP[seg][64][2048] (f32)
__global__ __launch_bounds__(256) void kD(const unsigned short* __restrict__ catB,
                                          const float* __restrict__ merge_w,
                                          float* __restrict__ mrgP) {
  __shared__ unsigned short As[64 * WPITCH];
  __shared__ unsigned short Ws[64 * WPITCH];
  int b  = blockIdx.x;            // 832 = 32 jt * 26 sg
  int jt = b / SEGM;
  int sg = b - jt * SEGM;         // 128-wide K segment
  const int t = threadIdx.x, row = t >> 2, kq = t & 3, w = t >> 6, l = t & 63;
  const uint4*  aRow = (const uint4*)catB + (size_t)row * 416 + sg * 16 + kq * 2;
  const float4* wRow = (const float4*)(merge_w + (size_t)(jt * 64 + row) * CM_
                                       + sg * 128 + kq * 16);
  f32x4 acc[4] = {{0,0,0,0},{0,0,0,0},{0,0,0,0},{0,0,0,0}};
  mfma_seg<2>(aRow, wRow, As, Ws, acc);
  float* outp = mrgP + (size_t)sg * (N_ * C_);
#pragma unroll
  for (int jm = 0; jm < 4; ++jm)
#pragma unroll
    for (int r = 0; r < 4; ++r)
      outp[(size_t)(16 * w + (l >> 4) * 4 + r) * C_ + jt * 64 + jm * 16 + (l & 15)]
        = acc[jm][r];
}

// reduce mrgP over segs + BN + ReLU + L2 normalize -> d_out (f32)
__global__ __launch_bounds__(256) void kE(const float* __restrict__ mrgP,
    const float* __restrict__ mb, const float* __restrict__ mg, const float* __restrict__ mbe,
    const float* __restrict__ mm, const float* __restrict__ mv,
    float* __restrict__ out) {
  int n = blockIdx.x, t = threadIdx.x;
  float z[8]; float ss = 0.f;
#pragma unroll
  for (int r = 0; r < 8; ++r) {
    int j = t + (r << 8);
    float y = 0.f;
#pragma unroll
    for (int sg = 0; sg < SEGM; ++sg) y += mrgP[(size_t)sg * (N_ * C_) + (size_t)n * C_ + j];
    float sc = mg[j] / sqrtf(mv[j] + 1e-5f);
    float v = (y + mb[j] - mm[j]) * sc + mbe[j];
    v = fmaxf(v, 0.f);
    z[r] = v; ss += v * v;
  }
#pragma unroll
  for (int off = 32; off; off >>= 1) ss += __shfl_xor(ss, off, 64);
  __shared__ float red[4];
  if ((t & 63) == 0) red[t >> 6] = ss;
  __syncthreads();
  float tot = red[0] + red[1] + red[2] + red[3];
  float inv = 1.f / fmaxf(sqrtf(tot), 1e-12f);
#pragma unroll
  for (int r = 0; r < 8; ++r) out[(size_t)n * C_ + t + (r << 8)] = z[r] * inv;
}

extern "C" void kernel_launch(void* const* d_in, const int* in_sizes, int n_in,
                              void* d_out, int out_size, void* d_ws, size_t ws_size,
                              hipStream_t stream) {
  const float* x          = (const float*)d_in[0];
  const float* poses      = (const float*)d_in[1];
  const float* local_w    = (const float*)d_in[2];
  const float* local_b    = (const float*)d_in[3];
  const float* local_g    = (const float*)d_in[4];
  const float* local_be   = (const float*)d_in[5];
  const float* local_m    = (const float*)d_in[6];
  const float* local_v    = (const float*)d_in[7];
  const float* merge_w    = (const float*)d_in[8];
  const float* merge_b    = (const float*)d_in[9];
  const float* merge_g    = (const float*)d_in[10];
  const float* merge_be   = (const float*)d_in[11];
  const float* merge_m    = (const float*)d_in[12];
  const float* merge_v    = (const float*)d_in[13];

  char* ws = (char*)d_ws;
  unsigned short* catB = (unsigned short*)ws;                 // 64*3328 bf16   = 425984 B
  unsigned short* avgB = (unsigned short*)(ws + 425984);      // 64*5*2048 bf16 = 1310720 B
  float* locP = (float*)(ws + 1736704);                       // 16*64*1280 f32 = 5242880 B
  float* mrgP = (float*)(ws + 6979584);                       // 26*64*2048 f32 = 13631488 B

  kB<<<512, 256, 0, stream>>>(x, poses, avgB, catB);
  kC<<<20 * SEGC, 256, 0, stream>>>(avgB, local_w, locP);
  kC2<<<(N_ * LOC_) / 256, 256, 0, stream>>>(locP, local_b, local_g, local_be,
                                             local_m, local_v, catB);
  kD<<<32 * SEGM, 256, 0, stream>>>(catB, merge_w, mrgP);
  kE<<<N_, 256, 0, stream>>>(mrgP, merge_b, merge_g, merge_be, merge_m, merge_v,
                             (float*)d_out);
}